// Round 10
// baseline (172.769 us; speedup 1.0000x reference)
//
#include <hip/hip_runtime.h>

#define KDIM 4096   // rows of x (= both i and j extents)
#define NDIM 1024   // feature dim
#define ALPHA 0.2f
#define LOG2E 1.4426950408889634f

typedef _Float16 h2    __attribute__((ext_vector_type(2)));
typedef _Float16 f16x8 __attribute__((ext_vector_type(8)));
typedef __attribute__((ext_vector_type(4))) float f32x4;

// P is never materialized: P_ij = max(E1_j*F1_i, E2_j*F2_i)  (select == max:
// the two lrelu branches cross exactly where they're equal, at s1+s2 = 0).
__device__ __align__(16) unsigned short g_xT [(size_t)NDIM * KDIM]; // 8 MB x^T f16
__device__ __align__(16) float          g_s1L[KDIM];
__device__ __align__(16) float          g_s2L[KDIM];
__device__ __align__(16) unsigned short g_E1h[KDIM];   // f16: exp2(s2L_j)
__device__ __align__(16) unsigned short g_E2h[KDIM];   // f16: exp2(ALPHA*s2L_j)
__device__ __align__(16) unsigned int   g_Fh [KDIM];   // packed f16 (F1_i, F2_i)
__device__ __align__(16) float          g_rZ [KDIM];

__device__ __forceinline__ unsigned short f2h(float f){
  _Float16 h = (_Float16)f;
  return *(unsigned short*)&h;
}

// ---- kernel 1: s1L/s2L = (x @ w1, x @ w2) * log2(e).  One wave per row. ----
__global__ __launch_bounds__(256) void k_dots(const float* __restrict__ x,
                                              const float* __restrict__ w){
  const int wid = threadIdx.x >> 6, lane = threadIdx.x & 63;
  const int row = blockIdx.x * 4 + wid;
  const float* xr = x + (size_t)row * NDIM;
  float d1 = 0.f, d2 = 0.f;
  #pragma unroll
  for (int q = 0; q < 4; ++q){
    const int off = q * 256 + lane * 4;
    float4 X  = *(const float4*)(xr + off);
    float4 W1 = *(const float4*)(w + off);
    float4 W2 = *(const float4*)(w + NDIM + off);
    d1 = fmaf(X.x, W1.x, fmaf(X.y, W1.y, fmaf(X.z, W1.z, fmaf(X.w, W1.w, d1))));
    d2 = fmaf(X.x, W2.x, fmaf(X.y, W2.y, fmaf(X.z, W2.z, fmaf(X.w, W2.w, d2))));
  }
  #pragma unroll
  for (int m = 32; m >= 1; m >>= 1){
    d1 += __shfl_xor(d1, m, 64);
    d2 += __shfl_xor(d2, m, 64);
  }
  if (lane == 0){
    g_s1L[row] = d1 * LOG2E;
    g_s2L[row] = d2 * LOG2E;
  }
}

// ---- kernel 2: fused transpose-tile + Z/F/E. 1024 blocks x 256 thr. ----
__global__ __launch_bounds__(256) void k_tzf(const float* __restrict__ x){
  __shared__ __align__(16) unsigned char smem[17408];
  const int tid = threadIdx.x;
  const int bid = blockIdx.x;

  { // Phase A: transpose one 64x64 tile of x -> g_xT (f16)
    unsigned short (*T)[80] = (unsigned short(*)[80])smem;   // 10.2 KB
    const int n0t = (bid & 15) * 64, j0t = (bid >> 4) * 64;
    #pragma unroll
    for (int it = 0; it < 4; ++it){
      const int idx = it * 256 + tid;
      const int r = idx >> 4, c4 = idx & 15;
      float4 v = *(const float4*)(x + (size_t)(j0t + r) * NDIM + n0t + c4 * 4);
      T[c4 * 4 + 0][r] = f2h(v.x);
      T[c4 * 4 + 1][r] = f2h(v.y);
      T[c4 * 4 + 2][r] = f2h(v.z);
      T[c4 * 4 + 3][r] = f2h(v.w);
    }
    __syncthreads();
    #pragma unroll
    for (int it = 0; it < 2; ++it){
      const int idx = it * 256 + tid;
      const int n = idx >> 3, cb = idx & 7;
      uint4 u = *(const uint4*)&T[n][cb * 8];
      *(uint4*)(g_xT + (size_t)(n0t + n) * KDIM + j0t + cb * 8) = u;
    }
    __syncthreads();   // before smem reuse
  }

  { // Phase B: m2 = max(s2L); rows bid*4..+3: F/rZ; E for j = bid*4..+3
    float* s2  = (float*)smem;              // 16 KB
    float* red = (float*)(smem + 16384);    // 1 KB
    float mx = -3.0e38f;
    {
      int i = tid * 4;
      #pragma unroll
      for (int c = 0; c < 4; ++c, i += 1024){
        float4 v = *(const float4*)&g_s2L[i];
        *(float4*)&s2[i] = v;
        mx = fmaxf(mx, fmaxf(fmaxf(v.x, v.y), fmaxf(v.z, v.w)));
      }
    }
    red[tid] = mx;
    __syncthreads();
    #pragma unroll
    for (int s = 128; s >= 1; s >>= 1){
      if (tid < s) red[tid] = fmaxf(red[tid], red[tid + s]);
      __syncthreads();
    }
    const float m2 = red[0];

    const int wid = tid >> 6, lane = tid & 63;
    const int row = bid * 4 + wid;
    const float s1 = g_s1L[row];
    const float t  = s1 + m2;
    const float mL = fmaxf(t, ALPHA * t);          // lrelu in log2 space
    const float F1 = __builtin_amdgcn_exp2f(s1 - mL);
    const float F2 = __builtin_amdgcn_exp2f(fmaf(ALPHA, s1, -mL));
    float z = 0.f;
    #pragma unroll 8
    for (int c = 0; c < 64; ++c){
      const float s = s2[c * 64 + lane];
      z += fmaxf(__builtin_amdgcn_exp2f(s) * F1,
                 __builtin_amdgcn_exp2f(ALPHA * s) * F2);
    }
    #pragma unroll
    for (int m = 32; m >= 1; m >>= 1) z += __shfl_xor(z, m, 64);
    if (lane == 0){
      g_rZ[row] = 1.0f / z;
      g_Fh[row] = (unsigned int)f2h(F1) | ((unsigned int)f2h(F2) << 16);
    }
    if (tid < 4){
      const int j = bid * 4 + tid;
      const float s = s2[j];
      g_E1h[j] = f2h(__builtin_amdgcn_exp2f(s));
      g_E2h[j] = f2h(__builtin_amdgcn_exp2f(ALPHA * s));
    }
  }
}

// ---- kernel 3: h += (P @ x)[k-half] * rZ.  Split-k x2, no LDS, no barriers. ----
// Wave 64m x 32n (mf=4, nf=2); block 256 thr = 4 waves (2m x 2n) = 128m x 64n.
// Grid 1024 = 512 output tiles x 2 k-halves -> 4 blocks/CU = 16 waves/CU.
// n-col = bid&15 keeps each XCD's 1 MB xT slice L2-resident (bid+512 lands on
// the same XCD: 512 % 8 == 0). A generated in-register from E/F as clean f16x8
// SSA ops (v_pk_mul/v_pk_max, no tuple repacking). Epilogue: f32 atomicAdd
// (out pre-zeroed by hipMemsetAsync; exactly 2 contenders per element).
__global__ __launch_bounds__(256) void k_gemm(float* __restrict__ out){
  const int tid  = threadIdx.x;
  const int wv   = tid >> 6, lane = tid & 63;
  const int quad = lane >> 4, l15 = lane & 15;
  const int bid  = blockIdx.x;
  const int bidl = bid & 511;
  const int kk   = bid >> 9;                         // k-half 0/1
  const int n0 = (bidl & 15) * 64 + (wv & 1) * 32;   // wave n-base
  const int m0 = (bidl >> 4) * 128 + (wv >> 1) * 64; // wave m-base
  const int kbase = kk * 2048;

  // Per-lane F splat vectors for the 4 m-frags (rows m0 + mf*16 + l15)
  f16x8 F1v[4], F2v[4];
  #pragma unroll
  for (int mf = 0; mf < 4; ++mf){
    const unsigned int fb = g_Fh[m0 + mf * 16 + l15];
    const h2 fp = *(const h2*)&fb;
    F1v[mf] = (f16x8){fp.x, fp.x, fp.x, fp.x, fp.x, fp.x, fp.x, fp.x};
    F2v[mf] = (f16x8){fp.y, fp.y, fp.y, fp.y, fp.y, fp.y, fp.y, fp.y};
  }

  // Row pointers: this lane's B rows (nf=0,1) and E chunk (quad-local).
  const unsigned short* bp0 = g_xT + (size_t)(n0 + l15) * KDIM + kbase + quad * 8;
  const unsigned short* bp1 = g_xT + (size_t)(n0 + 16 + l15) * KDIM + kbase + quad * 8;
  const unsigned short* e1p = g_E1h + kbase + quad * 8;
  const unsigned short* e2p = g_E2h + kbase + quad * 8;

  f32x4 acc[4][2] = {};
  f16x8 Bf[2][2], E1f[2], E2f[2];     // [parity][nf] register pipeline

  auto ld = [&](int kt, int p){
    const int o = kt * 32;            // elements (32 k per step)
    Bf[p][0] = *(const f16x8*)(bp0 + o);
    Bf[p][1] = *(const f16x8*)(bp1 + o);
    E1f[p]   = *(const f16x8*)(e1p + o);
    E2f[p]   = *(const f16x8*)(e2p + o);
  };
  auto step = [&](int p){
    #pragma unroll
    for (int mf = 0; mf < 4; ++mf){
      const f16x8 af = __builtin_elementwise_max(E1f[p] * F1v[mf],
                                                 E2f[p] * F2v[mf]);
      acc[mf][0] = __builtin_amdgcn_mfma_f32_16x16x32_f16(af, Bf[p][0], acc[mf][0], 0, 0, 0);
      acc[mf][1] = __builtin_amdgcn_mfma_f32_16x16x32_f16(af, Bf[p][1], acc[mf][1], 0, 0, 0);
    }
  };

  ld(0, 0);
  for (int kt2 = 0; kt2 < 32; ++kt2){
    const int kA = kt2 * 2;
    ld(kA + 1, 1);                 // prefetch overlaps step A
    step(0);
    if (kt2 < 31) ld(kA + 2, 0);   // prefetch overlaps step B
    step(1);
  }

  // epilogue: scale by 1/Z_i, accumulate. C/D layout: col=lane&15, row=quad*4+reg.
  #pragma unroll
  for (int mf = 0; mf < 4; ++mf){
    #pragma unroll
    for (int r = 0; r < 4; ++r){
      const int row = m0 + mf * 16 + quad * 4 + r;
      const float rz = g_rZ[row];
      #pragma unroll
      for (int nf = 0; nf < 2; ++nf)
        atomicAdd(out + (size_t)row * NDIM + n0 + nf * 16 + l15, acc[mf][nf][r] * rz);
    }
  }
}

extern "C" void kernel_launch(void* const* d_in, const int* in_sizes, int n_in,
                              void* d_out, int out_size, void* d_ws, size_t ws_size,
                              hipStream_t stream){
  const float* x = (const float*)d_in[0];   // f32 (4096x1024)
  const float* w = (const float*)d_in[1];   // f32 (2048)
  float* out = (float*)d_out;               // f32 (4096x1024)
  (void)in_sizes; (void)n_in; (void)d_ws; (void)ws_size;

  hipMemsetAsync(d_out, 0, (size_t)out_size * sizeof(float), stream);
  k_dots<<<dim3(1024), dim3(256), 0, stream>>>(x, w);
  k_tzf <<<dim3(1024), dim3(256), 0, stream>>>(x);
  k_gemm<<<dim3(1024), dim3(256), 0, stream>>>(out);
}